// Round 3
// baseline (1454.475 us; speedup 1.0000x reference)
//
#include <hip/hip_runtime.h>
#include <math.h>

#define BATCH 512
#define NG 16
#define GSZ 32
#define H 128
#define E 64
#define PRE 512
#define BOT 1024
#define MLPD 1024
#define SEQ 12
#define AK 1152   // Abf row length = H + BOT

typedef __attribute__((ext_vector_type(8))) short bf16x8;
typedef __attribute__((ext_vector_type(4))) float f32x4;
typedef __attribute__((ext_vector_type(16))) float f32x16;

__device__ __forceinline__ unsigned short f2bf(float f) {
    unsigned u = __float_as_uint(f);
    u += 0x7FFF + ((u >> 16) & 1);   // round-to-nearest-even
    return (unsigned short)(u >> 16);
}

#define GLB(p) ((const __attribute__((address_space(1))) unsigned int*)(p))
#define LDS(p) ((__attribute__((address_space(3))) unsigned int*)(p))

// ---------------------------------------------------------------- one-shot prep (all weight cvt + wc + init)
#define N0 (BOT * PRE)        /* W2b   */
#define N1 (MLPD * AK)        /* Wm1b  */
#define N2 (H * MLPD)         /* Wm2b  */
#define N3 (PRE * H)          /* W1hb  */
#define N4 (PRE)              /* wc    */
#define N5 (BATCH * H)        /* h/c   */
#define N6 (BATCH * 2)        /* pos   */
#define PREP_TOT (N0 + N1 + N2 + N3 + N4 + N5 + N6 + 1)

__global__ void prep_kernel(
    const float* __restrict__ W2, const float* __restrict__ Wm1,
    const float* __restrict__ Wm2, const float* __restrict__ W1,
    const float* __restrict__ Wp, const float* __restrict__ bp, const float* __restrict__ b1,
    const float* __restrict__ hh, const float* __restrict__ ch, const float* __restrict__ last_pos,
    unsigned short* __restrict__ W2b, unsigned short* __restrict__ Wm1b,
    unsigned short* __restrict__ Wm2b, unsigned short* __restrict__ W1hb,
    float* __restrict__ Wcx, float* __restrict__ Wcy, float* __restrict__ biash,
    float* __restrict__ hbuf, float* __restrict__ cbuf, float* __restrict__ pos,
    float* __restrict__ loss)
{
    long idx = (long)blockIdx.x * 256 + threadIdx.x;
    if (idx < N0) { W2b[idx] = f2bf(W2[idx]); return; }
    idx -= N0;
    if (idx < N1) { Wm1b[idx] = f2bf(Wm1[idx]); return; }
    idx -= N1;
    if (idx < N2) { Wm2b[idx] = f2bf(Wm2[idx]); return; }
    idx -= N2;
    if (idx < N3) { int r = (int)(idx >> 7), c = (int)(idx & 127);
                    W1hb[idx] = f2bf(W1[r * 192 + E + c]); return; }
    idx -= N3;
    if (idx < N4) {
        int p = (int)idx;
        float sx = 0.f, sy = 0.f, sb = 0.f;
#pragma unroll 8
        for (int e = 0; e < E; ++e) {
            float w = W1[p * 192 + e];
            sx += w * Wp[e * 2 + 0];
            sy += w * Wp[e * 2 + 1];
            sb += w * bp[e];
        }
        Wcx[p] = sx; Wcy[p] = sy; biash[p] = b1[p] + sb;
        return;
    }
    idx -= N4;
    if (idx < N5) { hbuf[idx] = hh[idx]; cbuf[idx] = ch[idx]; return; }
    idx -= N5;
    if (idx < N6) { pos[idx] = last_pos[idx]; return; }
    idx -= N6;
    if (idx == 0) *loss = 0.0f;
}

// ---------------------------------------------------------------- LSTM cell (+emb, +rel_pos, +loss)
__global__ __launch_bounds__(128) void lstm_step(
    const float* __restrict__ relin, const float* __restrict__ gt,
    const float* __restrict__ Wse, const float* __restrict__ bse,
    const float* __restrict__ Wih, const float* __restrict__ Whh,
    const float* __restrict__ bih, const float* __restrict__ bhh,
    const float* __restrict__ Wpos, const float* __restrict__ bpos,
    float* __restrict__ hbuf, float* __restrict__ cbuf,
    unsigned short* __restrict__ Abf,
    float* __restrict__ pos, float* __restrict__ traj, float* __restrict__ loss)
{
    int b = blockIdx.x, tid = threadIdx.x;
    __shared__ __align__(16) float xe[E];
    __shared__ __align__(16) float hp[H];
    __shared__ __align__(16) float hn[H];
    if (tid < E) {
        float rx = relin[b * 2 + 0], ry = relin[b * 2 + 1];
        xe[tid] = bse[tid] + Wse[tid * 2 + 0] * rx + Wse[tid * 2 + 1] * ry;
    }
    hp[tid] = hbuf[b * H + tid];
    __syncthreads();

    float g4[4];
    const float4* xev = (const float4*)xe;
    const float4* hpv = (const float4*)hp;
#pragma unroll
    for (int q = 0; q < 4; q++) {
        int row = q * H + tid;
        float acc = bih[row] + bhh[row];
        const float4* wi = (const float4*)(Wih + row * E);
#pragma unroll 4
        for (int k = 0; k < E / 4; k++) {
            float4 w = wi[k], x = xev[k];
            acc += w.x * x.x + w.y * x.y + w.z * x.z + w.w * x.w;
        }
        const float4* wh = (const float4*)(Whh + row * H);
#pragma unroll 4
        for (int k = 0; k < H / 4; k++) {
            float4 w = wh[k], x = hpv[k];
            acc += w.x * x.x + w.y * x.y + w.z * x.z + w.w * x.w;
        }
        g4[q] = acc;
    }
    float ig = 1.0f / (1.0f + expf(-g4[0]));
    float fg = 1.0f / (1.0f + expf(-g4[1]));
    float gg = tanhf(g4[2]);
    float og = 1.0f / (1.0f + expf(-g4[3]));
    float c = fg * cbuf[b * H + tid] + ig * gg;
    cbuf[b * H + tid] = c;
    float h = og * tanhf(c);
    Abf[(size_t)b * AK + tid] = f2bf(h);
    hn[tid] = h;
    __syncthreads();

    if (tid < 2) {
        float acc = bpos[tid];
        const float* wr = Wpos + tid * H;
        for (int k = 0; k < H; k++) acc += wr[k] * hn[k];
        float lp = pos[b * 2 + tid];
        pos[b * 2 + tid] = acc + lp;
        traj[b * 2 + tid] = acc;
        float d = acc - gt[b * 2 + tid];
        atomicAdd(loss, d * d * (1.0f / 1024.0f));
    }
}

// ---------------------------------------------------------------- x1 build (16B stores)
__global__ __launch_bounds__(256) void x1_build(
    const float* __restrict__ Hpartf, const float* __restrict__ pos,
    const float* __restrict__ Wcx, const float* __restrict__ Wcy,
    unsigned short* __restrict__ X1)
{
    int g = blockIdx.x >> 5, i = blockIdx.x & 31, tid = threadIdx.x;
    __shared__ float px[GSZ], py[GSZ];
    if (tid < GSZ) { px[tid] = pos[(g * GSZ + tid) * 2]; py[tid] = pos[(g * GSZ + tid) * 2 + 1]; }
    __syncthreads();
    int c0 = (tid & 63) * 8;
    int j0 = tid >> 6;
    float4 wxa = *(const float4*)&Wcx[c0], wxb = *(const float4*)&Wcx[c0 + 4];
    float4 wya = *(const float4*)&Wcy[c0], wyb = *(const float4*)&Wcy[c0 + 4];
    float pix = px[i], piy = py[i];
    size_t outbase = ((size_t)(g * GSZ + i) * GSZ) * PRE + c0;
#pragma unroll 2
    for (int jj = 0; jj < 8; ++jj) {
        int j = jj * 4 + j0;
        float rx = px[j] - pix, ry = py[j] - piy;
        const float4* hp = (const float4*)&Hpartf[(size_t)(g * GSZ + j) * PRE + c0];
        float4 ha = hp[0], hb = hp[1];
        union { ushort s[8]; uint4 v; } o;
        o.s[0] = f2bf(fmaxf(ha.x + rx * wxa.x + ry * wya.x, 0.f));
        o.s[1] = f2bf(fmaxf(ha.y + rx * wxa.y + ry * wya.y, 0.f));
        o.s[2] = f2bf(fmaxf(ha.z + rx * wxa.z + ry * wya.z, 0.f));
        o.s[3] = f2bf(fmaxf(ha.w + rx * wxa.w + ry * wya.w, 0.f));
        o.s[4] = f2bf(fmaxf(hb.x + rx * wxb.x + ry * wyb.x, 0.f));
        o.s[5] = f2bf(fmaxf(hb.y + rx * wxb.y + ry * wyb.y, 0.f));
        o.s[6] = f2bf(fmaxf(hb.z + rx * wxb.z + ry * wyb.z, 0.f));
        o.s[7] = f2bf(fmaxf(hb.w + rx * wxb.w + ry * wyb.w, 0.f));
        *(uint4*)&X1[outbase + (size_t)j * PRE] = o.v;
    }
}

// ---------------------------------------------------------------- generic bf16 MFMA GEMM  C = A(MxK) @ B(NxK)^T
// MODE 0: Cf = acc + bias (fp32) | MODE 1: Cb = bf16(relu(acc+bias)) | MODE 2: Cf = relu(acc+bias)
template <int BM, int BN, int MODE>
__global__ __launch_bounds__(256) void gemm_mfma(
    const unsigned short* __restrict__ A, int lda,
    const unsigned short* __restrict__ B, int ldb, int K,
    const float* __restrict__ bias,
    float* __restrict__ Cf, unsigned short* __restrict__ Cb, int ldc)
{
    constexpr int MT = BM / 32, NT = BN / 32;
    __shared__ __align__(16) unsigned short As[BM * 64];
    __shared__ __align__(16) unsigned short Bs[BN * 64];
    int tid = threadIdx.x;
    int lane = tid & 63, w = tid >> 6, wm = w >> 1, wn = w & 1;
    int quad = lane >> 4, l16 = lane & 15;
    int m0 = blockIdx.y * BM, n0 = blockIdx.x * BN;

    f32x4 acc[MT][NT];
#pragma unroll
    for (int mt = 0; mt < MT; ++mt)
#pragma unroll
        for (int nt = 0; nt < NT; ++nt) acc[mt][nt] = (f32x4)0.f;

    for (int k0 = 0; k0 < K; k0 += 64) {
#pragma unroll
        for (int it = 0; it < BM / 32; ++it) {
            int c = it * 256 + tid;
            __builtin_amdgcn_global_load_lds(
                GLB(A + (size_t)(m0 + (c >> 3)) * lda + k0 + (c & 7) * 8),
                LDS(&As[c * 8]), 16, 0, 0);
        }
#pragma unroll
        for (int it = 0; it < BN / 32; ++it) {
            int c = it * 256 + tid;
            __builtin_amdgcn_global_load_lds(
                GLB(B + (size_t)(n0 + (c >> 3)) * ldb + k0 + (c & 7) * 8),
                LDS(&Bs[c * 8]), 16, 0, 0);
        }
        __syncthreads();
#pragma unroll
        for (int ks = 0; ks < 2; ++ks) {
            bf16x8 af[MT], bfr[NT];
#pragma unroll
            for (int mt = 0; mt < MT; ++mt)
                af[mt] = *(const bf16x8*)&As[(wm * (BM / 2) + mt * 16 + l16) * 64 + ks * 32 + quad * 8];
#pragma unroll
            for (int nt = 0; nt < NT; ++nt)
                bfr[nt] = *(const bf16x8*)&Bs[(wn * (BN / 2) + nt * 16 + l16) * 64 + ks * 32 + quad * 8];
#pragma unroll
            for (int mt = 0; mt < MT; ++mt)
#pragma unroll
                for (int nt = 0; nt < NT; ++nt)
                    acc[mt][nt] = __builtin_amdgcn_mfma_f32_16x16x32_bf16(af[mt], bfr[nt], acc[mt][nt], 0, 0, 0);
        }
        __syncthreads();
    }

#pragma unroll
    for (int mt = 0; mt < MT; ++mt) {
        int rbase = m0 + wm * (BM / 2) + mt * 16 + quad * 4;
#pragma unroll
        for (int nt = 0; nt < NT; ++nt) {
            int col = n0 + wn * (BN / 2) + nt * 16 + l16;
            float bv = bias[col];
#pragma unroll
            for (int r = 0; r < 4; ++r) {
                float v = acc[mt][nt][r] + bv;
                if (MODE >= 1) v = fmaxf(v, 0.f);
                if (MODE == 1) Cb[(size_t)(rbase + r) * ldc + col] = f2bf(v);
                else           Cf[(size_t)(rbase + r) * ldc + col] = v;
            }
        }
    }
}

// ---------------------------------------------------------------- pool GEMM2 (32x32x16 MFMA) + max-over-j epilogue
__global__ __launch_bounds__(256) void pool_gemm(
    const unsigned short* __restrict__ X1, const unsigned short* __restrict__ W2b,
    const float* __restrict__ b2, unsigned short* __restrict__ Abf)
{
    constexpr int BM = 128, BN = 128;
    __shared__ __align__(16) unsigned short As[BM * 64];
    __shared__ __align__(16) unsigned short Bs[BN * 64];
    __shared__ float red[4 * 128];
    int tid = threadIdx.x;
    int lane = tid & 63, w = tid >> 6, wm = w >> 1, wn = w & 1;
    int m31 = lane & 31, kh = lane >> 5;   // A/B frag: elem = row lane&31, k-chunk lane>>5
    int m0 = blockIdx.y * BM, n0 = blockIdx.x * BN;

    f32x16 acc[2][2];
#pragma unroll
    for (int mt = 0; mt < 2; ++mt)
#pragma unroll
        for (int nt = 0; nt < 2; ++nt) acc[mt][nt] = (f32x16)0.f;

    for (int k0 = 0; k0 < PRE; k0 += 64) {
#pragma unroll
        for (int it = 0; it < 4; ++it) {
            int c = it * 256 + tid;
            __builtin_amdgcn_global_load_lds(
                GLB(X1 + (size_t)(m0 + (c >> 3)) * PRE + k0 + (c & 7) * 8),
                LDS(&As[c * 8]), 16, 0, 0);
        }
#pragma unroll
        for (int it = 0; it < 4; ++it) {
            int c = it * 256 + tid;
            __builtin_amdgcn_global_load_lds(
                GLB(W2b + (size_t)(n0 + (c >> 3)) * PRE + k0 + (c & 7) * 8),
                LDS(&Bs[c * 8]), 16, 0, 0);
        }
        __syncthreads();
#pragma unroll
        for (int ks = 0; ks < 4; ++ks) {
            bf16x8 af[2], bfr[2];
#pragma unroll
            for (int mt = 0; mt < 2; ++mt)
                af[mt] = *(const bf16x8*)&As[(wm * 64 + mt * 32 + m31) * 64 + ks * 16 + kh * 8];
#pragma unroll
            for (int nt = 0; nt < 2; ++nt)
                bfr[nt] = *(const bf16x8*)&Bs[(wn * 64 + nt * 32 + m31) * 64 + ks * 16 + kh * 8];
#pragma unroll
            for (int mt = 0; mt < 2; ++mt)
#pragma unroll
                for (int nt = 0; nt < 2; ++nt)
                    acc[mt][nt] = __builtin_amdgcn_mfma_f32_32x32x16_bf16(af[mt], bfr[nt], acc[mt][nt], 0, 0, 0);
        }
        __syncthreads();
    }

    // each 32x32 tile spans exactly one j-unit; cols = base + (lane&31)
#pragma unroll
    for (int mt = 0; mt < 2; ++mt)
#pragma unroll
    for (int nt = 0; nt < 2; ++nt) {
        float v = acc[mt][nt][0];
#pragma unroll
        for (int r = 1; r < 16; ++r) v = fmaxf(v, acc[mt][nt][r]);
        v = fmaxf(v, __shfl_xor(v, 32));
        if (lane < 32) red[(wm * 2 + mt) * 128 + wn * 64 + nt * 32 + m31] = v;
    }
    __syncthreads();
    for (int e = tid; e < 512; e += 256) {
        int u = e >> 7, cc = e & 127;
        int gu = blockIdx.y * 4 + u;                 // batch row (g*32+i)
        float v = fmaxf(red[e] + b2[n0 + cc], 0.f);
        Abf[(size_t)gu * AK + H + n0 + cc] = f2bf(v);
    }
}

// ---------------------------------------------------------------- launch
extern "C" void kernel_launch(void* const* d_in, const int* in_sizes, int n_in,
                              void* d_out, int out_size, void* d_ws, size_t ws_size,
                              hipStream_t stream)
{
    const float* last_pos     = (const float*)d_in[0];
    const float* last_pos_rel = (const float*)d_in[1];
    const float* hh           = (const float*)d_in[2];
    const float* ch           = (const float*)d_in[3];
    const float* ptr_rel      = (const float*)d_in[4];
    const float* Wih  = (const float*)d_in[6];
    const float* Whh  = (const float*)d_in[7];
    const float* bih  = (const float*)d_in[8];
    const float* bhh  = (const float*)d_in[9];
    const float* Wse  = (const float*)d_in[10];
    const float* bse  = (const float*)d_in[11];
    const float* Wpos = (const float*)d_in[12];
    const float* bpos = (const float*)d_in[13];
    const float* Wp   = (const float*)d_in[14];
    const float* bp   = (const float*)d_in[15];
    const float* W1   = (const float*)d_in[16];
    const float* b1   = (const float*)d_in[17];
    const float* W2   = (const float*)d_in[18];
    const float* b2   = (const float*)d_in[19];
    const float* Wm1  = (const float*)d_in[20];
    const float* bm1  = (const float*)d_in[21];
    const float* Wm2  = (const float*)d_in[22];
    const float* bm2  = (const float*)d_in[23];

    float* ws     = (float*)d_ws;
    float* hbuf   = ws;                       // 65536
    float* cbuf   = hbuf + BATCH * H;         // 65536
    float* pos    = cbuf + BATCH * H;         // 1024
    float* Hpartf = pos + 1024;               // 262144
    float* Wcx    = Hpartf + BATCH * PRE;     // 512
    float* Wcy    = Wcx + PRE;                // 512
    float* biash  = Wcy + PRE;                // 512
    unsigned short* ub    = (unsigned short*)(biash + PRE);
    unsigned short* Abf   = ub;                         // 512*1152
    unsigned short* X1    = Abf + (size_t)BATCH * AK;   // 16384*512
    unsigned short* dhbf  = X1 + (size_t)16384 * PRE;   // 512*1024
    unsigned short* W2b   = dhbf + (size_t)BATCH * MLPD;
    unsigned short* Wm1b  = W2b + (size_t)BOT * PRE;
    unsigned short* Wm2b  = Wm1b + (size_t)MLPD * AK;
    unsigned short* W1hb  = Wm2b + (size_t)H * MLPD;

    float* out  = (float*)d_out;
    float* loss = out + SEQ * BATCH * 2;

    prep_kernel<<<(PREP_TOT + 255) / 256, 256, 0, stream>>>(
        W2, Wm1, Wm2, W1, Wp, bp, b1, hh, ch, last_pos,
        W2b, Wm1b, Wm2b, W1hb, Wcx, Wcy, biash, hbuf, cbuf, pos, loss);

    for (int t = 0; t < SEQ; t++) {
        const float* relin = (t == 0) ? last_pos_rel : (ptr_rel + (t - 1) * BATCH * 2);
        const float* gt = ptr_rel + t * BATCH * 2;
        lstm_step<<<BATCH, 128, 0, stream>>>(relin, gt, Wse, bse, Wih, Whh, bih, bhh,
                                             Wpos, bpos, hbuf, cbuf, Abf, pos,
                                             out + t * BATCH * 2, loss);
        if (t == SEQ - 1) break;   // h after last step is dead — only traj/loss needed
        // Hpart = h @ W1h^T + (b1 + W1e@bp)   [512x512, K=128]
        gemm_mfma<64, 64, 0><<<dim3(PRE / 64, BATCH / 64), 256, 0, stream>>>(
            Abf, AK, W1hb, H, H, biash, Hpartf, nullptr, PRE);
        x1_build<<<NG * GSZ, 256, 0, stream>>>(Hpartf, pos, Wcx, Wcy, X1);
        // X2 + max_j -> Abf[:,128:]   [16384x1024, K=512]
        pool_gemm<<<dim3(BOT / 128, 16384 / 128), 256, 0, stream>>>(X1, W2b, b2, Abf);
        // dh = relu([h|pool] @ Wm1^T + bm1)   [512x1024, K=1152] -> bf16
        gemm_mfma<64, 64, 1><<<dim3(MLPD / 64, BATCH / 64), 256, 0, stream>>>(
            Abf, AK, Wm1b, AK, AK, bm1, nullptr, dhbf, MLPD);
        // h = relu(dh @ Wm2^T + bm2)   [512x128, K=1024] -> fp32 hbuf
        gemm_mfma<64, 32, 2><<<dim3(H / 32, BATCH / 64), 256, 0, stream>>>(
            dhbf, MLPD, Wm2b, MLPD, MLPD, bm2, hbuf, nullptr, H);
    }
}

// Round 4
// 1294.261 us; speedup vs baseline: 1.1238x; 1.1238x over previous
//
#include <hip/hip_runtime.h>
#include <math.h>

#define BATCH 512
#define NG 16
#define GSZ 32
#define H 128
#define E 64
#define PRE 512
#define BOT 1024
#define MLPD 1024
#define SEQ 12
#define AK 1152   // Abf row length = H + BOT

typedef __attribute__((ext_vector_type(8))) short bf16x8;
typedef __attribute__((ext_vector_type(4))) float f32x4;

__device__ __forceinline__ unsigned short f2bf(float f) {
    unsigned u = __float_as_uint(f);
    u += 0x7FFF + ((u >> 16) & 1);   // round-to-nearest-even
    return (unsigned short)(u >> 16);
}

#define GLB(p) ((const __attribute__((address_space(1))) unsigned int*)(p))
#define LDS(p) ((__attribute__((address_space(3))) unsigned int*)(p))

// ---------------------------------------------------------------- one-shot prep (all weight cvt + wc + init)
#define N0 (BOT * PRE)        /* W2b   */
#define N1 (MLPD * AK)        /* Wm1b  */
#define N2 (H * MLPD)         /* Wm2b  */
#define N3 (PRE * H)          /* W1hb  */
#define N4 (PRE)              /* wc    */
#define N5 (BATCH * H)        /* h/c   */
#define N6 (BATCH * 2)        /* pos   */
#define PREP_TOT (N0 + N1 + N2 + N3 + N4 + N5 + N6 + 1)

__global__ void prep_kernel(
    const float* __restrict__ W2, const float* __restrict__ Wm1,
    const float* __restrict__ Wm2, const float* __restrict__ W1,
    const float* __restrict__ Wp, const float* __restrict__ bp, const float* __restrict__ b1,
    const float* __restrict__ hh, const float* __restrict__ ch, const float* __restrict__ last_pos,
    unsigned short* __restrict__ W2b, unsigned short* __restrict__ Wm1b,
    unsigned short* __restrict__ Wm2b, unsigned short* __restrict__ W1hb,
    float* __restrict__ Wcx, float* __restrict__ Wcy, float* __restrict__ biash,
    float* __restrict__ hbuf, float* __restrict__ cbuf, float* __restrict__ pos,
    float* __restrict__ loss)
{
    long idx = (long)blockIdx.x * 256 + threadIdx.x;
    if (idx < N0) { W2b[idx] = f2bf(W2[idx]); return; }
    idx -= N0;
    if (idx < N1) { Wm1b[idx] = f2bf(Wm1[idx]); return; }
    idx -= N1;
    if (idx < N2) { Wm2b[idx] = f2bf(Wm2[idx]); return; }
    idx -= N2;
    if (idx < N3) { int r = (int)(idx >> 7), c = (int)(idx & 127);
                    W1hb[idx] = f2bf(W1[r * 192 + E + c]); return; }
    idx -= N3;
    if (idx < N4) {
        int p = (int)idx;
        float sx = 0.f, sy = 0.f, sb = 0.f;
#pragma unroll 8
        for (int e = 0; e < E; ++e) {
            float w = W1[p * 192 + e];
            sx += w * Wp[e * 2 + 0];
            sy += w * Wp[e * 2 + 1];
            sb += w * bp[e];
        }
        Wcx[p] = sx; Wcy[p] = sy; biash[p] = b1[p] + sb;
        return;
    }
    idx -= N4;
    if (idx < N5) { hbuf[idx] = hh[idx]; cbuf[idx] = ch[idx]; return; }
    idx -= N5;
    if (idx < N6) { pos[idx] = last_pos[idx]; return; }
    idx -= N6;
    if (idx == 0) *loss = 0.0f;
}

// ---------------------------------------------------------------- LSTM cell (+emb, +rel_pos, +loss)
__global__ __launch_bounds__(128) void lstm_step(
    const float* __restrict__ relin, const float* __restrict__ gt,
    const float* __restrict__ Wse, const float* __restrict__ bse,
    const float* __restrict__ Wih, const float* __restrict__ Whh,
    const float* __restrict__ bih, const float* __restrict__ bhh,
    const float* __restrict__ Wpos, const float* __restrict__ bpos,
    float* __restrict__ hbuf, float* __restrict__ cbuf,
    unsigned short* __restrict__ Abf,
    float* __restrict__ pos, float* __restrict__ traj, float* __restrict__ loss)
{
    int b = blockIdx.x, tid = threadIdx.x;
    __shared__ __align__(16) float xe[E];
    __shared__ __align__(16) float hp[H];
    __shared__ __align__(16) float hn[H];
    if (tid < E) {
        float rx = relin[b * 2 + 0], ry = relin[b * 2 + 1];
        xe[tid] = bse[tid] + Wse[tid * 2 + 0] * rx + Wse[tid * 2 + 1] * ry;
    }
    hp[tid] = hbuf[b * H + tid];
    __syncthreads();

    float g4[4];
    const float4* xev = (const float4*)xe;
    const float4* hpv = (const float4*)hp;
#pragma unroll
    for (int q = 0; q < 4; q++) {
        int row = q * H + tid;
        float acc = bih[row] + bhh[row];
        const float4* wi = (const float4*)(Wih + row * E);
#pragma unroll 4
        for (int k = 0; k < E / 4; k++) {
            float4 w = wi[k], x = xev[k];
            acc += w.x * x.x + w.y * x.y + w.z * x.z + w.w * x.w;
        }
        const float4* wh = (const float4*)(Whh + row * H);
#pragma unroll 4
        for (int k = 0; k < H / 4; k++) {
            float4 w = wh[k], x = hpv[k];
            acc += w.x * x.x + w.y * x.y + w.z * x.z + w.w * x.w;
        }
        g4[q] = acc;
    }
    float ig = 1.0f / (1.0f + expf(-g4[0]));
    float fg = 1.0f / (1.0f + expf(-g4[1]));
    float gg = tanhf(g4[2]);
    float og = 1.0f / (1.0f + expf(-g4[3]));
    float c = fg * cbuf[b * H + tid] + ig * gg;
    cbuf[b * H + tid] = c;
    float h = og * tanhf(c);
    Abf[(size_t)b * AK + tid] = f2bf(h);
    hn[tid] = h;
    __syncthreads();

    if (tid < 2) {
        float acc = bpos[tid];
        const float* wr = Wpos + tid * H;
        for (int k = 0; k < H; k++) acc += wr[k] * hn[k];
        float lp = pos[b * 2 + tid];
        pos[b * 2 + tid] = acc + lp;
        traj[b * 2 + tid] = acc;
        float d = acc - gt[b * 2 + tid];
        atomicAdd(loss, d * d * (1.0f / 1024.0f));
    }
}

// ---------------------------------------------------------------- x1 build (16B stores)
__global__ __launch_bounds__(256) void x1_build(
    const float* __restrict__ Hpartf, const float* __restrict__ pos,
    const float* __restrict__ Wcx, const float* __restrict__ Wcy,
    unsigned short* __restrict__ X1)
{
    int g = blockIdx.x >> 5, i = blockIdx.x & 31, tid = threadIdx.x;
    __shared__ float px[GSZ], py[GSZ];
    if (tid < GSZ) { px[tid] = pos[(g * GSZ + tid) * 2]; py[tid] = pos[(g * GSZ + tid) * 2 + 1]; }
    __syncthreads();
    int c0 = (tid & 63) * 8;
    int j0 = tid >> 6;
    float4 wxa = *(const float4*)&Wcx[c0], wxb = *(const float4*)&Wcx[c0 + 4];
    float4 wya = *(const float4*)&Wcy[c0], wyb = *(const float4*)&Wcy[c0 + 4];
    float pix = px[i], piy = py[i];
    size_t outbase = ((size_t)(g * GSZ + i) * GSZ) * PRE + c0;
#pragma unroll 2
    for (int jj = 0; jj < 8; ++jj) {
        int j = jj * 4 + j0;
        float rx = px[j] - pix, ry = py[j] - piy;
        const float4* hp = (const float4*)&Hpartf[(size_t)(g * GSZ + j) * PRE + c0];
        float4 ha = hp[0], hb = hp[1];
        union { ushort s[8]; uint4 v; } o;
        o.s[0] = f2bf(fmaxf(ha.x + rx * wxa.x + ry * wya.x, 0.f));
        o.s[1] = f2bf(fmaxf(ha.y + rx * wxa.y + ry * wya.y, 0.f));
        o.s[2] = f2bf(fmaxf(ha.z + rx * wxa.z + ry * wya.z, 0.f));
        o.s[3] = f2bf(fmaxf(ha.w + rx * wxa.w + ry * wya.w, 0.f));
        o.s[4] = f2bf(fmaxf(hb.x + rx * wxb.x + ry * wyb.x, 0.f));
        o.s[5] = f2bf(fmaxf(hb.y + rx * wxb.y + ry * wyb.y, 0.f));
        o.s[6] = f2bf(fmaxf(hb.z + rx * wxb.z + ry * wyb.z, 0.f));
        o.s[7] = f2bf(fmaxf(hb.w + rx * wxb.w + ry * wyb.w, 0.f));
        *(uint4*)&X1[outbase + (size_t)j * PRE] = o.v;
    }
}

// ---------------------------------------------------------------- generic bf16 MFMA GEMM  C = A(MxK) @ B(NxK)^T
// MODE 0: Cf = acc + bias (fp32) | MODE 1: Cb = bf16(relu(acc+bias)) | MODE 2: Cf = relu(acc+bias)
template <int BM, int BN, int MODE>
__global__ __launch_bounds__(256) void gemm_mfma(
    const unsigned short* __restrict__ A, int lda,
    const unsigned short* __restrict__ B, int ldb, int K,
    const float* __restrict__ bias,
    float* __restrict__ Cf, unsigned short* __restrict__ Cb, int ldc)
{
    constexpr int MT = BM / 32, NT = BN / 32;
    __shared__ __align__(16) unsigned short As[BM * 64];
    __shared__ __align__(16) unsigned short Bs[BN * 64];
    int tid = threadIdx.x;
    int lane = tid & 63, w = tid >> 6, wm = w >> 1, wn = w & 1;
    int quad = lane >> 4, l16 = lane & 15;
    int m0 = blockIdx.y * BM, n0 = blockIdx.x * BN;

    f32x4 acc[MT][NT];
#pragma unroll
    for (int mt = 0; mt < MT; ++mt)
#pragma unroll
        for (int nt = 0; nt < NT; ++nt) acc[mt][nt] = (f32x4)0.f;

    for (int k0 = 0; k0 < K; k0 += 64) {
#pragma unroll
        for (int it = 0; it < BM / 32; ++it) {
            int c = it * 256 + tid;
            __builtin_amdgcn_global_load_lds(
                GLB(A + (size_t)(m0 + (c >> 3)) * lda + k0 + (c & 7) * 8),
                LDS(&As[c * 8]), 16, 0, 0);
        }
#pragma unroll
        for (int it = 0; it < BN / 32; ++it) {
            int c = it * 256 + tid;
            __builtin_amdgcn_global_load_lds(
                GLB(B + (size_t)(n0 + (c >> 3)) * ldb + k0 + (c & 7) * 8),
                LDS(&Bs[c * 8]), 16, 0, 0);
        }
        __syncthreads();
#pragma unroll
        for (int ks = 0; ks < 2; ++ks) {
            bf16x8 af[MT], bfr[NT];
#pragma unroll
            for (int mt = 0; mt < MT; ++mt)
                af[mt] = *(const bf16x8*)&As[(wm * (BM / 2) + mt * 16 + l16) * 64 + ks * 32 + quad * 8];
#pragma unroll
            for (int nt = 0; nt < NT; ++nt)
                bfr[nt] = *(const bf16x8*)&Bs[(wn * (BN / 2) + nt * 16 + l16) * 64 + ks * 32 + quad * 8];
#pragma unroll
            for (int mt = 0; mt < MT; ++mt)
#pragma unroll
                for (int nt = 0; nt < NT; ++nt)
                    acc[mt][nt] = __builtin_amdgcn_mfma_f32_16x16x32_bf16(af[mt], bfr[nt], acc[mt][nt], 0, 0, 0);
        }
        __syncthreads();
    }

#pragma unroll
    for (int mt = 0; mt < MT; ++mt) {
        int rbase = m0 + wm * (BM / 2) + mt * 16 + quad * 4;
#pragma unroll
        for (int nt = 0; nt < NT; ++nt) {
            int col = n0 + wn * (BN / 2) + nt * 16 + l16;
            float bv = bias[col];
#pragma unroll
            for (int r = 0; r < 4; ++r) {
                float v = acc[mt][nt][r] + bv;
                if (MODE >= 1) v = fmaxf(v, 0.f);
                if (MODE == 1) Cb[(size_t)(rbase + r) * ldc + col] = f2bf(v);
                else           Cf[(size_t)(rbase + r) * ldc + col] = v;
            }
        }
    }
}

// ---------------------------------------------------------------- pool GEMM2 (16x16x32 MFMA, XCD-swizzled) + max-over-j
// grid = 1024 1D. XCD k (= bid%8) owns m-tiles [16k,16k+16) x all 8 n-tiles:
// per-XCD working set = 2MB X1 slice + 1MB W2b < 4MB L2 -> X1 fetched from HBM once.
__global__ __launch_bounds__(256) void pool_gemm(
    const unsigned short* __restrict__ X1, const unsigned short* __restrict__ W2b,
    const float* __restrict__ b2, unsigned short* __restrict__ Abf)
{
    constexpr int BM = 128, BN = 128, MT = 4, NT = 4;
    __shared__ __align__(16) unsigned short As[BM * 64];
    __shared__ __align__(16) unsigned short Bs[BN * 64];
    __shared__ float red[4 * 128];
    int tid = threadIdx.x;
    int lane = tid & 63, w = tid >> 6, wm = w >> 1, wn = w & 1;
    int quad = lane >> 4, l16 = lane & 15;
    int bid = blockIdx.x;
    int m_tile = ((bid & 7) << 4) | (bid >> 6);   // xcd*16 + slow index
    int n_tile = (bid >> 3) & 7;                  // n varies fastest within an XCD
    int m0 = m_tile * BM, n0 = n_tile * BN;

    f32x4 acc[MT][NT];
#pragma unroll
    for (int mt = 0; mt < MT; ++mt)
#pragma unroll
        for (int nt = 0; nt < NT; ++nt) acc[mt][nt] = (f32x4)0.f;

    for (int k0 = 0; k0 < PRE; k0 += 64) {
#pragma unroll
        for (int it = 0; it < 4; ++it) {
            int c = it * 256 + tid;
            __builtin_amdgcn_global_load_lds(
                GLB(X1 + (size_t)(m0 + (c >> 3)) * PRE + k0 + (c & 7) * 8),
                LDS(&As[c * 8]), 16, 0, 0);
        }
#pragma unroll
        for (int it = 0; it < 4; ++it) {
            int c = it * 256 + tid;
            __builtin_amdgcn_global_load_lds(
                GLB(W2b + (size_t)(n0 + (c >> 3)) * PRE + k0 + (c & 7) * 8),
                LDS(&Bs[c * 8]), 16, 0, 0);
        }
        __syncthreads();
#pragma unroll
        for (int ks = 0; ks < 2; ++ks) {
            bf16x8 af[MT], bfr[NT];
#pragma unroll
            for (int mt = 0; mt < MT; ++mt)
                af[mt] = *(const bf16x8*)&As[(wm * 64 + mt * 16 + l16) * 64 + ks * 32 + quad * 8];
#pragma unroll
            for (int nt = 0; nt < NT; ++nt)
                bfr[nt] = *(const bf16x8*)&Bs[(wn * 64 + nt * 16 + l16) * 64 + ks * 32 + quad * 8];
#pragma unroll
            for (int mt = 0; mt < MT; ++mt)
#pragma unroll
                for (int nt = 0; nt < NT; ++nt)
                    acc[mt][nt] = __builtin_amdgcn_mfma_f32_16x16x32_bf16(af[mt], bfr[nt], acc[mt][nt], 0, 0, 0);
        }
        __syncthreads();
    }

    // max over j: rows of a 32-row j-unit = {mt pair} x {4 quads} x {4 regs}
#pragma unroll
    for (int nt = 0; nt < NT; ++nt) {
        float u0 = -1e30f, u1 = -1e30f;
#pragma unroll
        for (int r = 0; r < 4; ++r) {
            u0 = fmaxf(u0, fmaxf(acc[0][nt][r], acc[1][nt][r]));
            u1 = fmaxf(u1, fmaxf(acc[2][nt][r], acc[3][nt][r]));
        }
        u0 = fmaxf(u0, __shfl_xor(u0, 16)); u0 = fmaxf(u0, __shfl_xor(u0, 32));
        u1 = fmaxf(u1, __shfl_xor(u1, 16)); u1 = fmaxf(u1, __shfl_xor(u1, 32));
        if (lane < 16) {
            red[(wm * 2 + 0) * 128 + wn * 64 + nt * 16 + lane] = u0;
            red[(wm * 2 + 1) * 128 + wn * 64 + nt * 16 + lane] = u1;
        }
    }
    __syncthreads();
    for (int e = tid; e < 512; e += 256) {
        int u = e >> 7, cc = e & 127;
        int gu = m_tile * 4 + u;                 // batch row (g*32+i)
        float v = fmaxf(red[e] + b2[n0 + cc], 0.f);
        Abf[(size_t)gu * AK + H + n0 + cc] = f2bf(v);
    }
}

// ---------------------------------------------------------------- launch
extern "C" void kernel_launch(void* const* d_in, const int* in_sizes, int n_in,
                              void* d_out, int out_size, void* d_ws, size_t ws_size,
                              hipStream_t stream)
{
    const float* last_pos     = (const float*)d_in[0];
    const float* last_pos_rel = (const float*)d_in[1];
    const float* hh           = (const float*)d_in[2];
    const float* ch           = (const float*)d_in[3];
    const float* ptr_rel      = (const float*)d_in[4];
    const float* Wih  = (const float*)d_in[6];
    const float* Whh  = (const float*)d_in[7];
    const float* bih  = (const float*)d_in[8];
    const float* bhh  = (const float*)d_in[9];
    const float* Wse  = (const float*)d_in[10];
    const float* bse  = (const float*)d_in[11];
    const float* Wpos = (const float*)d_in[12];
    const float* bpos = (const float*)d_in[13];
    const float* Wp   = (const float*)d_in[14];
    const float* bp   = (const float*)d_in[15];
    const float* W1   = (const float*)d_in[16];
    const float* b1   = (const float*)d_in[17];
    const float* W2   = (const float*)d_in[18];
    const float* b2   = (const float*)d_in[19];
    const float* Wm1  = (const float*)d_in[20];
    const float* bm1  = (const float*)d_in[21];
    const float* Wm2  = (const float*)d_in[22];
    const float* bm2  = (const float*)d_in[23];

    float* ws     = (float*)d_ws;
    float* hbuf   = ws;                       // 65536
    float* cbuf   = hbuf + BATCH * H;         // 65536
    float* pos    = cbuf + BATCH * H;         // 1024
    float* Hpartf = pos + 1024;               // 262144
    float* Wcx    = Hpartf + BATCH * PRE;     // 512
    float* Wcy    = Wcx + PRE;                // 512
    float* biash  = Wcy + PRE;                // 512
    unsigned short* ub    = (unsigned short*)(biash + PRE);
    unsigned short* Abf   = ub;                         // 512*1152
    unsigned short* X1    = Abf + (size_t)BATCH * AK;   // 16384*512
    unsigned short* dhbf  = X1 + (size_t)16384 * PRE;   // 512*1024
    unsigned short* W2b   = dhbf + (size_t)BATCH * MLPD;
    unsigned short* Wm1b  = W2b + (size_t)BOT * PRE;
    unsigned short* Wm2b  = Wm1b + (size_t)MLPD * AK;
    unsigned short* W1hb  = Wm2b + (size_t)H * MLPD;

    float* out  = (float*)d_out;
    float* loss = out + SEQ * BATCH * 2;

    prep_kernel<<<(PREP_TOT + 255) / 256, 256, 0, stream>>>(
        W2, Wm1, Wm2, W1, Wp, bp, b1, hh, ch, last_pos,
        W2b, Wm1b, Wm2b, W1hb, Wcx, Wcy, biash, hbuf, cbuf, pos, loss);

    for (int t = 0; t < SEQ; t++) {
        const float* relin = (t == 0) ? last_pos_rel : (ptr_rel + (t - 1) * BATCH * 2);
        const float* gt = ptr_rel + t * BATCH * 2;
        lstm_step<<<BATCH, 128, 0, stream>>>(relin, gt, Wse, bse, Wih, Whh, bih, bhh,
                                             Wpos, bpos, hbuf, cbuf, Abf, pos,
                                             out + t * BATCH * 2, loss);
        if (t == SEQ - 1) break;   // h after last step is dead — only traj/loss needed
        // Hpart = h @ W1h^T + (b1 + W1e@bp)   [512x512, K=128]
        gemm_mfma<64, 64, 0><<<dim3(PRE / 64, BATCH / 64), 256, 0, stream>>>(
            Abf, AK, W1hb, H, H, biash, Hpartf, nullptr, PRE);
        x1_build<<<NG * GSZ, 256, 0, stream>>>(Hpartf, pos, Wcx, Wcy, X1);
        // X2 + max_j -> Abf[:,128:]   [16384x1024, K=512]
        pool_gemm<<<1024, 256, 0, stream>>>(X1, W2b, b2, Abf);
        // dh = relu([h|pool] @ Wm1^T + bm1)   [512x1024, K=1152] -> bf16
        gemm_mfma<64, 64, 1><<<dim3(MLPD / 64, BATCH / 64), 256, 0, stream>>>(
            Abf, AK, Wm1b, AK, AK, bm1, nullptr, dhbf, MLPD);
        // h = relu(dh @ Wm2^T + bm2)   [512x128, K=1024] -> fp32 hbuf
        gemm_mfma<64, 32, 2><<<dim3(H / 32, BATCH / 64), 256, 0, stream>>>(
            dhbf, MLPD, Wm2b, MLPD, MLPD, bm2, hbuf, nullptr, H);
    }
}

// Round 5
// 1190.158 us; speedup vs baseline: 1.2221x; 1.0875x over previous
//
#include <hip/hip_runtime.h>
#include <math.h>

#define BATCH 512
#define NG 16
#define GSZ 32
#define H 128
#define E 64
#define PRE 512
#define BOT 1024
#define MLPD 1024
#define SEQ 12
#define AK 1152   // Abf row length = H + BOT

typedef __attribute__((ext_vector_type(8))) short bf16x8;
typedef __attribute__((ext_vector_type(4))) float f32x4;

__device__ __forceinline__ unsigned short f2bf(float f) {
    unsigned u = __float_as_uint(f);
    u += 0x7FFF + ((u >> 16) & 1);   // round-to-nearest-even
    return (unsigned short)(u >> 16);
}

#define GLB(p) ((const __attribute__((address_space(1))) unsigned int*)(p))
#define LDS(p) ((__attribute__((address_space(3))) unsigned int*)(p))

// ---------------------------------------------------------------- one-shot prep (all weight cvt + wc + init)
#define N0 (BOT * PRE)        /* W2b   */
#define N1 (MLPD * AK)        /* Wm1b  */
#define N2 (H * MLPD)         /* Wm2b  */
#define N3 (PRE * H)          /* W1hb  */
#define N4 (PRE)              /* wc    */
#define N5 (BATCH * H)        /* h/c   */
#define N6 (BATCH * 2)        /* pos   */
#define PREP_TOT (N0 + N1 + N2 + N3 + N4 + N5 + N6 + 1)

__global__ void prep_kernel(
    const float* __restrict__ W2, const float* __restrict__ Wm1,
    const float* __restrict__ Wm2, const float* __restrict__ W1,
    const float* __restrict__ Wp, const float* __restrict__ bp, const float* __restrict__ b1,
    const float* __restrict__ hh, const float* __restrict__ ch, const float* __restrict__ last_pos,
    unsigned short* __restrict__ W2b, unsigned short* __restrict__ Wm1b,
    unsigned short* __restrict__ Wm2b, unsigned short* __restrict__ W1hb,
    float* __restrict__ Wcx, float* __restrict__ Wcy, float* __restrict__ biash,
    float* __restrict__ hbuf, float* __restrict__ cbuf, float* __restrict__ pos,
    float* __restrict__ loss)
{
    long idx = (long)blockIdx.x * 256 + threadIdx.x;
    if (idx < N0) { W2b[idx] = f2bf(W2[idx]); return; }
    idx -= N0;
    if (idx < N1) { Wm1b[idx] = f2bf(Wm1[idx]); return; }
    idx -= N1;
    if (idx < N2) { Wm2b[idx] = f2bf(Wm2[idx]); return; }
    idx -= N2;
    if (idx < N3) { int r = (int)(idx >> 7), c = (int)(idx & 127);
                    W1hb[idx] = f2bf(W1[r * 192 + E + c]); return; }
    idx -= N3;
    if (idx < N4) {
        int p = (int)idx;
        float sx = 0.f, sy = 0.f, sb = 0.f;
#pragma unroll 8
        for (int e = 0; e < E; ++e) {
            float w = W1[p * 192 + e];
            sx += w * Wp[e * 2 + 0];
            sy += w * Wp[e * 2 + 1];
            sb += w * bp[e];
        }
        Wcx[p] = sx; Wcy[p] = sy; biash[p] = b1[p] + sb;
        return;
    }
    idx -= N4;
    if (idx < N5) { hbuf[idx] = hh[idx]; cbuf[idx] = ch[idx]; return; }
    idx -= N5;
    if (idx < N6) { pos[idx] = last_pos[idx]; return; }
    idx -= N6;
    if (idx == 0) *loss = 0.0f;
}

// ---------------------------------------------------------------- LSTM cell (+emb, +rel_pos, +loss)
__global__ __launch_bounds__(128) void lstm_step(
    const float* __restrict__ relin, const float* __restrict__ gt,
    const float* __restrict__ Wse, const float* __restrict__ bse,
    const float* __restrict__ Wih, const float* __restrict__ Whh,
    const float* __restrict__ bih, const float* __restrict__ bhh,
    const float* __restrict__ Wpos, const float* __restrict__ bpos,
    float* __restrict__ hbuf, float* __restrict__ cbuf,
    unsigned short* __restrict__ Abf,
    float* __restrict__ pos, float* __restrict__ traj, float* __restrict__ loss)
{
    int b = blockIdx.x, tid = threadIdx.x;
    __shared__ __align__(16) float xe[E];
    __shared__ __align__(16) float hp[H];
    __shared__ __align__(16) float hn[H];
    if (tid < E) {
        float rx = relin[b * 2 + 0], ry = relin[b * 2 + 1];
        xe[tid] = bse[tid] + Wse[tid * 2 + 0] * rx + Wse[tid * 2 + 1] * ry;
    }
    hp[tid] = hbuf[b * H + tid];
    __syncthreads();

    float g4[4];
    const float4* xev = (const float4*)xe;
    const float4* hpv = (const float4*)hp;
#pragma unroll
    for (int q = 0; q < 4; q++) {
        int row = q * H + tid;
        float acc = bih[row] + bhh[row];
        const float4* wi = (const float4*)(Wih + row * E);
#pragma unroll 4
        for (int k = 0; k < E / 4; k++) {
            float4 w = wi[k], x = xev[k];
            acc += w.x * x.x + w.y * x.y + w.z * x.z + w.w * x.w;
        }
        const float4* wh = (const float4*)(Whh + row * H);
#pragma unroll 4
        for (int k = 0; k < H / 4; k++) {
            float4 w = wh[k], x = hpv[k];
            acc += w.x * x.x + w.y * x.y + w.z * x.z + w.w * x.w;
        }
        g4[q] = acc;
    }
    float ig = 1.0f / (1.0f + expf(-g4[0]));
    float fg = 1.0f / (1.0f + expf(-g4[1]));
    float gg = tanhf(g4[2]);
    float og = 1.0f / (1.0f + expf(-g4[3]));
    float c = fg * cbuf[b * H + tid] + ig * gg;
    cbuf[b * H + tid] = c;
    float h = og * tanhf(c);
    Abf[(size_t)b * AK + tid] = f2bf(h);
    hn[tid] = h;
    __syncthreads();

    if (tid < 2) {
        float acc = bpos[tid];
        const float* wr = Wpos + tid * H;
        for (int k = 0; k < H; k++) acc += wr[k] * hn[k];
        float lp = pos[b * 2 + tid];
        pos[b * 2 + tid] = acc + lp;
        traj[b * 2 + tid] = acc;
        float d = acc - gt[b * 2 + tid];
        atomicAdd(loss, d * d * (1.0f / 1024.0f));
    }
}

// ---------------------------------------------------------------- generic bf16 MFMA GEMM  C = A(MxK) @ B(NxK)^T
// MODE 0: Cf = acc + bias (fp32) | MODE 1: Cb = bf16(relu(acc+bias)) | MODE 2: Cf = relu(acc+bias)
template <int BM, int BN, int MODE>
__global__ __launch_bounds__(256) void gemm_mfma(
    const unsigned short* __restrict__ A, int lda,
    const unsigned short* __restrict__ B, int ldb, int K,
    const float* __restrict__ bias,
    float* __restrict__ Cf, unsigned short* __restrict__ Cb, int ldc)
{
    constexpr int MT = BM / 32, NT = BN / 32;
    __shared__ __align__(16) unsigned short As[BM * 64];
    __shared__ __align__(16) unsigned short Bs[BN * 64];
    int tid = threadIdx.x;
    int lane = tid & 63, w = tid >> 6, wm = w >> 1, wn = w & 1;
    int quad = lane >> 4, l16 = lane & 15;
    int m0 = blockIdx.y * BM, n0 = blockIdx.x * BN;

    f32x4 acc[MT][NT];
#pragma unroll
    for (int mt = 0; mt < MT; ++mt)
#pragma unroll
        for (int nt = 0; nt < NT; ++nt) acc[mt][nt] = (f32x4)0.f;

    for (int k0 = 0; k0 < K; k0 += 64) {
#pragma unroll
        for (int it = 0; it < BM / 32; ++it) {
            int c = it * 256 + tid;
            __builtin_amdgcn_global_load_lds(
                GLB(A + (size_t)(m0 + (c >> 3)) * lda + k0 + (c & 7) * 8),
                LDS(&As[c * 8]), 16, 0, 0);
        }
#pragma unroll
        for (int it = 0; it < BN / 32; ++it) {
            int c = it * 256 + tid;
            __builtin_amdgcn_global_load_lds(
                GLB(B + (size_t)(n0 + (c >> 3)) * ldb + k0 + (c & 7) * 8),
                LDS(&Bs[c * 8]), 16, 0, 0);
        }
        __syncthreads();
#pragma unroll
        for (int ks = 0; ks < 2; ++ks) {
            bf16x8 af[MT], bfr[NT];
#pragma unroll
            for (int mt = 0; mt < MT; ++mt)
                af[mt] = *(const bf16x8*)&As[(wm * (BM / 2) + mt * 16 + l16) * 64 + ks * 32 + quad * 8];
#pragma unroll
            for (int nt = 0; nt < NT; ++nt)
                bfr[nt] = *(const bf16x8*)&Bs[(wn * (BN / 2) + nt * 16 + l16) * 64 + ks * 32 + quad * 8];
#pragma unroll
            for (int mt = 0; mt < MT; ++mt)
#pragma unroll
                for (int nt = 0; nt < NT; ++nt)
                    acc[mt][nt] = __builtin_amdgcn_mfma_f32_16x16x32_bf16(af[mt], bfr[nt], acc[mt][nt], 0, 0, 0);
        }
        __syncthreads();
    }

#pragma unroll
    for (int mt = 0; mt < MT; ++mt) {
        int rbase = m0 + wm * (BM / 2) + mt * 16 + quad * 4;
#pragma unroll
        for (int nt = 0; nt < NT; ++nt) {
            int col = n0 + wn * (BN / 2) + nt * 16 + l16;
            float bv = bias[col];
#pragma unroll
            for (int r = 0; r < 4; ++r) {
                float v = acc[mt][nt][r] + bv;
                if (MODE >= 1) v = fmaxf(v, 0.f);
                if (MODE == 1) Cb[(size_t)(rbase + r) * ldc + col] = f2bf(v);
                else           Cf[(size_t)(rbase + r) * ldc + col] = v;
            }
        }
    }
}

// ---------------------------------------------------------------- pool GEMM2, fused x1 A-tile build (no X1 in HBM)
// m_tile (0..127): g = m_tile>>3, iq = m_tile&7; rows = u*32+j -> (g, i=iq*4+u, j)
// A[row][k] = bf16(relu(Hpart[g,j,k] + rx(i,j)*Wcx[k] + ry(i,j)*Wcy[k]))  built in LDS per k-slice.
// XCD swizzle: xcd = bid&7 owns 16 consecutive m-tiles x all 8 n-tiles (W2b slice L2-resident).
__global__ __launch_bounds__(256) void pool_gemm(
    const float* __restrict__ Hpartf, const float* __restrict__ pos,
    const float* __restrict__ Wcx, const float* __restrict__ Wcy,
    const unsigned short* __restrict__ W2b,
    const float* __restrict__ b2, unsigned short* __restrict__ Abf)
{
    constexpr int BM = 128, BN = 128, MT = 4, NT = 4;
    constexpr int LDA = 72;   // +8 bf16 pad: 144B row stride kills 8-way ds_write conflicts, keeps 16B align
    __shared__ __align__(16) unsigned short As[BM * LDA];  // 18 KB
    __shared__ __align__(16) unsigned short Bs[BN * 64];   // 16 KB
    __shared__ float red[4 * 128];
    __shared__ float px[GSZ], py[GSZ];
    int tid = threadIdx.x;
    int lane = tid & 63, w = tid >> 6, wm = w >> 1, wn = w & 1;
    int quad = lane >> 4, l16 = lane & 15;
    int bid = blockIdx.x;
    int m_tile = ((bid & 7) << 4) | (bid >> 6);
    int n_tile = (bid >> 3) & 7;
    int g = m_tile >> 3, iq = m_tile & 7;
    int n0 = n_tile * BN;

    if (tid < GSZ) { px[tid] = pos[(g * GSZ + tid) * 2]; py[tid] = pos[(g * GSZ + tid) * 2 + 1]; }

    f32x4 acc[MT][NT];
#pragma unroll
    for (int mt = 0; mt < MT; ++mt)
#pragma unroll
        for (int nt = 0; nt < NT; ++nt) acc[mt][nt] = (f32x4)0.f;

    // A-build thread mapping: j = tid>>3 (0..31), k8 = (tid&7)*8
    int jA = tid >> 3, k8 = (tid & 7) * 8;
    __syncthreads();   // px/py visible
    float pjx = px[jA], pjy = py[jA];

    for (int k0 = 0; k0 < PRE; k0 += 64) {
        // stage B k-slice (async direct-to-LDS)
#pragma unroll
        for (int it = 0; it < 4; ++it) {
            int c = it * 256 + tid;
            __builtin_amdgcn_global_load_lds(
                GLB(W2b + (size_t)(n0 + (c >> 3)) * PRE + k0 + (c & 7) * 8),
                LDS(&Bs[c * 8]), 16, 0, 0);
        }
        // build A k-slice in LDS from Hpart (global, L2-hot) + affine rel-pos term
        {
            const float4* hp4 = (const float4*)&Hpartf[(size_t)(g * GSZ + jA) * PRE + k0 + k8];
            float4 ha = hp4[0], hb = hp4[1];
            float4 wxa = *(const float4*)&Wcx[k0 + k8], wxb = *(const float4*)&Wcx[k0 + k8 + 4];
            float4 wya = *(const float4*)&Wcy[k0 + k8], wyb = *(const float4*)&Wcy[k0 + k8 + 4];
#pragma unroll
            for (int u = 0; u < 4; ++u) {
                int i = iq * 4 + u;
                float rx = pjx - px[i], ry = pjy - py[i];
                union { ushort s[8]; uint4 v; } o;
                o.s[0] = f2bf(fmaxf(ha.x + rx * wxa.x + ry * wya.x, 0.f));
                o.s[1] = f2bf(fmaxf(ha.y + rx * wxa.y + ry * wya.y, 0.f));
                o.s[2] = f2bf(fmaxf(ha.z + rx * wxa.z + ry * wya.z, 0.f));
                o.s[3] = f2bf(fmaxf(ha.w + rx * wxa.w + ry * wya.w, 0.f));
                o.s[4] = f2bf(fmaxf(hb.x + rx * wxb.x + ry * wyb.x, 0.f));
                o.s[5] = f2bf(fmaxf(hb.y + rx * wxb.y + ry * wyb.y, 0.f));
                o.s[6] = f2bf(fmaxf(hb.z + rx * wxb.z + ry * wyb.z, 0.f));
                o.s[7] = f2bf(fmaxf(hb.w + rx * wxb.w + ry * wyb.w, 0.f));
                *(uint4*)&As[(u * GSZ + jA) * LDA + k8] = o.v;
            }
        }
        __syncthreads();   // As written (ds) + Bs arrived (vmcnt drained by barrier)
#pragma unroll
        for (int ks = 0; ks < 2; ++ks) {
            bf16x8 af[MT], bfr[NT];
#pragma unroll
            for (int mt = 0; mt < MT; ++mt)
                af[mt] = *(const bf16x8*)&As[(wm * 64 + mt * 16 + l16) * LDA + ks * 32 + quad * 8];
#pragma unroll
            for (int nt = 0; nt < NT; ++nt)
                bfr[nt] = *(const bf16x8*)&Bs[(wn * 64 + nt * 16 + l16) * 64 + ks * 32 + quad * 8];
#pragma unroll
            for (int mt = 0; mt < MT; ++mt)
#pragma unroll
                for (int nt = 0; nt < NT; ++nt)
                    acc[mt][nt] = __builtin_amdgcn_mfma_f32_16x16x32_bf16(af[mt], bfr[nt], acc[mt][nt], 0, 0, 0);
        }
        __syncthreads();   // done reading As/Bs before overwrite
    }

    // max over j within each 32-row j-unit: unit u = {mt=2u,2u+1} x {4 quads} x {4 regs}
#pragma unroll
    for (int nt = 0; nt < NT; ++nt) {
        float u0 = -1e30f, u1 = -1e30f;
#pragma unroll
        for (int r = 0; r < 4; ++r) {
            u0 = fmaxf(u0, fmaxf(acc[0][nt][r], acc[1][nt][r]));
            u1 = fmaxf(u1, fmaxf(acc[2][nt][r], acc[3][nt][r]));
        }
        u0 = fmaxf(u0, __shfl_xor(u0, 16)); u0 = fmaxf(u0, __shfl_xor(u0, 32));
        u1 = fmaxf(u1, __shfl_xor(u1, 16)); u1 = fmaxf(u1, __shfl_xor(u1, 32));
        if (lane < 16) {
            red[(wm * 2 + 0) * 128 + wn * 64 + nt * 16 + lane] = u0;
            red[(wm * 2 + 1) * 128 + wn * 64 + nt * 16 + lane] = u1;
        }
    }
    __syncthreads();
    for (int e = tid; e < 512; e += 256) {
        int u = e >> 7, cc = e & 127;
        int gu = m_tile * 4 + u;                 // batch row (g*32+i)
        float v = fmaxf(red[e] + b2[n0 + cc], 0.f);
        Abf[(size_t)gu * AK + H + n0 + cc] = f2bf(v);
    }
}

// ---------------------------------------------------------------- launch
extern "C" void kernel_launch(void* const* d_in, const int* in_sizes, int n_in,
                              void* d_out, int out_size, void* d_ws, size_t ws_size,
                              hipStream_t stream)
{
    const float* last_pos     = (const float*)d_in[0];
    const float* last_pos_rel = (const float*)d_in[1];
    const float* hh           = (const float*)d_in[2];
    const float* ch           = (const float*)d_in[3];
    const float* ptr_rel      = (const float*)d_in[4];
    const float* Wih  = (const float*)d_in[6];
    const float* Whh  = (const float*)d_in[7];
    const float* bih  = (const float*)d_in[8];
    const float* bhh  = (const float*)d_in[9];
    const float* Wse  = (const float*)d_in[10];
    const float* bse  = (const float*)d_in[11];
    const float* Wpos = (const float*)d_in[12];
    const float* bpos = (const float*)d_in[13];
    const float* Wp   = (const float*)d_in[14];
    const float* bp   = (const float*)d_in[15];
    const float* W1   = (const float*)d_in[16];
    const float* b1   = (const float*)d_in[17];
    const float* W2   = (const float*)d_in[18];
    const float* b2   = (const float*)d_in[19];
    const float* Wm1  = (const float*)d_in[20];
    const float* bm1  = (const float*)d_in[21];
    const float* Wm2  = (const float*)d_in[22];
    const float* bm2  = (const float*)d_in[23];

    float* ws     = (float*)d_ws;
    float* hbuf   = ws;                       // 65536
    float* cbuf   = hbuf + BATCH * H;         // 65536
    float* pos    = cbuf + BATCH * H;         // 1024
    float* Hpartf = pos + 1024;               // 262144
    float* Wcx    = Hpartf + BATCH * PRE;     // 512
    float* Wcy    = Wcx + PRE;                // 512
    float* biash  = Wcy + PRE;                // 512
    unsigned short* ub    = (unsigned short*)(biash + PRE);
    unsigned short* Abf   = ub;                         // 512*1152
    unsigned short* dhbf  = Abf + (size_t)BATCH * AK;   // 512*1024
    unsigned short* W2b   = dhbf + (size_t)BATCH * MLPD;
    unsigned short* Wm1b  = W2b + (size_t)BOT * PRE;
    unsigned short* Wm2b  = Wm1b + (size_t)MLPD * AK;
    unsigned short* W1hb  = Wm2b + (size_t)H * MLPD;

    float* out  = (float*)d_out;
    float* loss = out + SEQ * BATCH * 2;

    prep_kernel<<<(PREP_TOT + 255) / 256, 256, 0, stream>>>(
        W2, Wm1, Wm2, W1, Wp, bp, b1, hh, ch, last_pos,
        W2b, Wm1b, Wm2b, W1hb, Wcx, Wcy, biash, hbuf, cbuf, pos, loss);

    for (int t = 0; t < SEQ; t++) {
        const float* relin = (t == 0) ? last_pos_rel : (ptr_rel + (t - 1) * BATCH * 2);
        const float* gt = ptr_rel + t * BATCH * 2;
        lstm_step<<<BATCH, 128, 0, stream>>>(relin, gt, Wse, bse, Wih, Whh, bih, bhh,
                                             Wpos, bpos, hbuf, cbuf, Abf, pos,
                                             out + t * BATCH * 2, loss);
        if (t == SEQ - 1) break;   // h after last step is dead — only traj/loss needed
        // Hpart = h @ W1h^T + (b1 + W1e@bp)   [512x512, K=128]
        gemm_mfma<64, 64, 0><<<dim3(PRE / 64, BATCH / 64), 256, 0, stream>>>(
            Abf, AK, W1hb, H, H, biash, Hpartf, nullptr, PRE);
        // pool: fused x1-build + X2 GEMM + max_j -> Abf[:,128:]
        pool_gemm<<<1024, 256, 0, stream>>>(Hpartf, pos, Wcx, Wcy, W2b, b2, Abf);
        // dh = relu([h|pool] @ Wm1^T + bm1)   [512x1024, K=1152] -> bf16
        gemm_mfma<64, 64, 1><<<dim3(MLPD / 64, BATCH / 64), 256, 0, stream>>>(
            Abf, AK, Wm1b, AK, AK, bm1, nullptr, dhbf, MLPD);
        // h = relu(dh @ Wm2^T + bm2)   [512x128, K=1024] -> fp32 hbuf
        gemm_mfma<64, 32, 2><<<dim3(H / 32, BATCH / 64), 256, 0, stream>>>(
            dhbf, MLPD, Wm2b, MLPD, MLPD, bm2, hbuf, nullptr, H);
    }
}